// Round 1
// baseline (30330.542 us; speedup 1.0000x reference)
//
#include <hip/hip_runtime.h>
#include <stdint.h>

#define T_MAX 512
#define BATCH 64
#define NCLS  128
#define BEAM  32
#define TBL   6144
#define NEGF  (-1e30f)
#define EMPTYK ((int)0x80000000)
#define HPRIME 1000003u

// jnp.logaddexp: max + log1p(exp(-|a-b|)) (all values finite here)
__device__ __forceinline__ float lae(float a, float b) {
  float mx = fmaxf(a, b);
  return mx + log1pf(expf(-fabsf(a - b)));
}
// monotonic float <-> uint mapping for atomicMax on floats
__device__ __forceinline__ unsigned encf(float x) {
  unsigned b = __float_as_uint(x);
  return (b & 0x80000000u) ? ~b : (b | 0x80000000u);
}
__device__ __forceinline__ float decf(unsigned u) {
  unsigned b = (u & 0x80000000u) ? (u ^ 0x80000000u) : ~u;
  return __uint_as_float(b);
}

__device__ __forceinline__ int tbl_insert(int* key, int h) {
  unsigned x = (unsigned)h * 2654435761u;
  x ^= x >> 16;
  int j = (int)(((unsigned long long)x * (unsigned long long)TBL) >> 32);
  for (;;) {
    int cur = key[j];
    if (cur == EMPTYK) cur = atomicCAS(&key[j], EMPTYK, h);
    if (cur == EMPTYK || cur == h) return j;
    ++j; if (j == TBL) j = 0;
  }
}

__global__ __launch_bounds__(512, 1)
void ctc_beam_kernel(const float* __restrict__ data,
                     const int* __restrict__ dlen,
                     int* __restrict__ out) {
  __shared__ int       tkey[TBL];
  __shared__ unsigned  tmax[TBL];   // pass1: enc(max pnb); pass3: bits of pnb_m
  __shared__ unsigned  tsum[TBL];   // pass2: f32 sum; pass3: enc(tot)
  __shared__ unsigned  tmin[TBL];   // min original candidate flat index
  __shared__ unsigned short bp[T_MAX * BEAM];  // backpointers: parent|cls<<5|ext<<12
  __shared__ float lp[NCLS];
  __shared__ int   bhash[2][BEAM];
  __shared__ float bpb[2][BEAM], bpnb[2][BEAM];
  __shared__ int   blen[2][BEAM], blast[2][BEAM];
  __shared__ float sptot[BEAM];
  __shared__ int   stay_slot[BEAM];
  __shared__ float stay_pb[BEAM], stay_x[BEAM];
  __shared__ unsigned long long wkey[8 * BEAM];
  __shared__ unsigned widx[8 * BEAM];
  __shared__ unsigned sel[BEAM];
  __shared__ int seqbuf[T_MAX];
  __shared__ int flen_s;

  const int tid = threadIdx.x;
  const int b = blockIdx.x;
  int L = dlen[b];
  L = L < 0 ? 0 : (L > T_MAX ? T_MAX : L);

  if (tid < BEAM) {
    bhash[0][tid] = tid;                     // hashes0 = arange(W)
    bpb[0][tid]   = (tid == 0) ? 0.0f : NEGF;
    bpnb[0][tid]  = NEGF;
    blen[0][tid]  = 0;
    blast[0][tid] = -1;
  }
  __syncthreads();

  int cb = 0;
  for (int t = 0; t < L; ++t) {
    // ---- clear table + load log-probs for this (t, b)
    for (int m = tid; m < TBL; m += 512) {
      tkey[m] = EMPTYK; tmax[m] = 0u; tsum[m] = 0u; tmin[m] = 0xFFFFFFFFu;
    }
    if (tid < NCLS) lp[tid] = data[((size_t)t * BATCH + b) * NCLS + tid];
    __syncthreads();

    // ---- per-beam ptot
    if (tid < BEAM) sptot[tid] = lae(bpb[cb][tid], bpnb[cb][tid]);
    __syncthreads();

    // ---- insert candidates: 4096 extends (8/thread) + 32 stays
    int eslot[8]; float ex_[8];
    {
      const int i   = tid >> 4;          // beam index (16 threads per beam)
      const int c0  = (tid & 15) << 3;   // 8 consecutive classes
      const float pbi = bpb[cb][i];
      const float pti = sptot[i];
      const int   lsti = blast[cb][i];
      const unsigned hb = (unsigned)bhash[cb][i] * HPRIME;
      #pragma unroll
      for (int k = 0; k < 8; ++k) {
        const int c = c0 + k;
        int h = (int)(hb + (unsigned)(c + 1));
        if (h == EMPTYK) h = (int)0x80000001u;  // sentinel dodge (consistent remap)
        const float x = (c == 0) ? NEGF : (((c == lsti) ? pbi : pti) + lp[c]);
        const int s = tbl_insert(tkey, h);
        atomicMax(&tmax[s], encf(x));
        atomicMin(&tmin[s], (unsigned)(BEAM + i * NCLS + c));
        eslot[k] = s; ex_[k] = x;
      }
    }
    if (tid < BEAM) {
      const int i = tid;
      const int lsti = blast[cb][i];
      const float lpl = (lsti >= 0) ? lp[lsti] : NEGF;
      const float spb = sptot[i] + lp[0];        // stay pb = ptot + lp[blank]
      const float sx  = bpnb[cb][i] + lpl;       // stay pnb = pnb + lp[last]
      const int s = tbl_insert(tkey, bhash[cb][i]);
      atomicMax(&tmax[s], encf(sx));
      atomicMin(&tmin[s], (unsigned)i);
      stay_slot[i] = s; stay_pb[i] = spb; stay_x[i] = sx;
    }
    __syncthreads();

    // ---- pass 2: sum exp(x - m) per segment
    #pragma unroll
    for (int k = 0; k < 8; ++k) {
      const int s = eslot[k];
      atomicAdd((float*)&tsum[s], expf(ex_[k] - decf(tmax[s])));
    }
    if (tid < BEAM) {
      const int s = stay_slot[tid];
      atomicAdd((float*)&tsum[s], expf(stay_x[tid] - decf(tmax[s])));
    }
    __syncthreads();

    // ---- per-slot: pnb_m and tot (assuming no stay; fixed up below)
    for (int m = tid; m < TBL; m += 512) {
      if (tkey[m] != EMPTYK) {
        const float mm = decf(tmax[m]);
        const float ss = __uint_as_float(tsum[m]);
        const float pnbm = mm + logf(ss);
        tmax[m] = __float_as_uint(pnbm);
        tsum[m] = encf(lae(NEGF, pnbm));
      }
    }
    __syncthreads();
    // stays: tot = lae(stay_pb, pnb_m)  (pb_m == stay_pb exactly; <=1 stay/slot)
    if (tid < BEAM) {
      const int s = stay_slot[tid];
      tsum[s] = encf(lae(stay_pb[tid], __uint_as_float(tmax[s])));
    }
    __syncthreads();

    // ---- selection: key = (enc(tot) << 32) | (smaller signed hash ranks higher)
    {
      const int wv = tid >> 6, ln = tid & 63;
      const int base = wv * (TBL / 8) + ln * (TBL / 512);
      unsigned long long kk[TBL / 512];
      #pragma unroll
      for (int m = 0; m < TBL / 512; ++m) {
        const int idx = base + m;
        if (tkey[idx] != EMPTYK) {
          const unsigned hh = (unsigned)tkey[idx] ^ 0x80000000u;
          kk[m] = ((unsigned long long)tsum[idx] << 32) |
                  (unsigned long long)(0xFFFFFFFFu - hh);
        } else kk[m] = 0ull;
      }
      unsigned cons = 0;
      for (int it = 0; it < BEAM; ++it) {
        unsigned long long best = 0ull; int bi = -1;
        #pragma unroll
        for (int m = 0; m < TBL / 512; ++m)
          if (!((cons >> m) & 1u) && kk[m] > best) { best = kk[m]; bi = m; }
        unsigned long long wm = best;
        #pragma unroll
        for (int off = 32; off > 0; off >>= 1) {
          const unsigned long long o = __shfl_xor(wm, off, 64);
          if (o > wm) wm = o;
        }
        const unsigned long long ball = __ballot(best == wm && wm != 0ull);
        const int winner = ball ? (__ffsll((long long)ball) - 1) : -1;
        if (ln == winner) {
          cons |= 1u << bi;
          wkey[wv * BEAM + it] = wm;
          widx[wv * BEAM + it] = (unsigned)(base + bi);
        } else if (winner < 0 && ln == 0) {
          wkey[wv * BEAM + it] = 0ull;
          widx[wv * BEAM + it] = 0xFFFFFFFFu;
        }
      }
    }
    __syncthreads();
    if (tid < 64) {  // wave 0 merges 8x32 -> ordered top-32
      unsigned long long kk[4]; unsigned ii[4];
      #pragma unroll
      for (int m = 0; m < 4; ++m) { kk[m] = wkey[tid * 4 + m]; ii[m] = widx[tid * 4 + m]; }
      unsigned cons = 0;
      for (int it = 0; it < BEAM; ++it) {
        unsigned long long best = 0ull; int bi = -1;
        #pragma unroll
        for (int m = 0; m < 4; ++m)
          if (!((cons >> m) & 1u) && kk[m] > best) { best = kk[m]; bi = m; }
        unsigned long long wm = best;
        #pragma unroll
        for (int off = 32; off > 0; off >>= 1) {
          const unsigned long long o = __shfl_xor(wm, off, 64);
          if (o > wm) wm = o;
        }
        const unsigned long long ball = __ballot(best == wm && wm != 0ull);
        const int winner = ball ? (__ffsll((long long)ball) - 1) : -1;
        if (tid == winner) { cons |= 1u << bi; sel[it] = ii[bi]; }
        else if (winner < 0 && tid == 0) sel[it] = 0xFFFFFFFFu;
      }
    }
    __syncthreads();

    // ---- update beam state (thread j = new beam rank j)
    if (tid < BEAM) {
      const int j = tid;
      const unsigned s = sel[j];
      int nh, p, cls, ex; float npb, npnb;
      if (s != 0xFFFFFFFFu) {
        nh = tkey[s];
        npnb = __uint_as_float(tmax[s]);
        npb = NEGF;
        #pragma unroll
        for (int i = 0; i < BEAM; ++i)
          if (stay_slot[i] == (int)s) npb = stay_pb[i];
        const unsigned mi = tmin[s];         // = order[top_idx] (segment head)
        ex  = (mi >= BEAM) ? 1 : 0;
        p   = ex ? (int)((mi - BEAM) >> 7) : (int)mi;
        cls = ex ? (int)((mi - BEAM) & 127) : 0;
        p &= 31;
      } else {  // <32 alive segments: cannot happen (>=127 alive); keep safe
        nh = 0x7F000000 + j; npb = NEGF; npnb = NEGF; p = j; cls = 0; ex = 0;
      }
      const int plen = blen[cb][p], plast = blast[cb][p];
      const int nb = cb ^ 1;
      bhash[nb][j] = nh; bpb[nb][j] = npb; bpnb[nb][j] = npnb;
      blen[nb][j]  = plen + ex;
      blast[nb][j] = ex ? cls : plast;
      bp[t * BEAM + j] = (unsigned short)(p | (cls << 5) | (ex << 12));
    }
    __syncthreads();
    cb ^= 1;
  }

  // ---- final top-1 + path reconstruction via backpointers
  if (tid == 0) {
    float bt = -3.4e38f; int bj = 0;
    for (int j = 0; j < BEAM; ++j) {
      const float tt = lae(bpb[cb][j], bpnb[cb][j]);
      if (tt > bt) { bt = tt; bj = j; }   // strict > : lowest index wins ties
    }
    int cur = bj;
    int pos = blen[cb][bj];
    flen_s = pos;
    for (int tt = L - 1; tt >= 0; --tt) {
      const unsigned short e = bp[tt * BEAM + cur];
      const int p = e & 31, cl = (e >> 5) & 127, ex = (e >> 12) & 1;
      if (ex) { --pos; if (pos >= 0) seqbuf[pos] = cl; }
      cur = p;
    }
  }
  __syncthreads();
  const int fl = flen_s;
  for (int k = tid; k < T_MAX; k += 512) {
    out[(size_t)b * T_MAX + k] = (k < fl) ? seqbuf[k] : 0;
  }
}

extern "C" void kernel_launch(void* const* d_in, const int* in_sizes, int n_in,
                              void* d_out, int out_size, void* d_ws, size_t ws_size,
                              hipStream_t stream) {
  const float* data = (const float*)d_in[0];   // [512, 64, 128] f32 log-probs
  const int*   dlen = (const int*)d_in[1];     // [64] int32
  int* out = (int*)d_out;                      // [64, 512] int32
  (void)in_sizes; (void)n_in; (void)out_size; (void)d_ws; (void)ws_size;
  hipLaunchKernelGGL(ctc_beam_kernel, dim3(BATCH), dim3(512), 0, stream,
                     data, dlen, out);
}

// Round 2
// 15381.424 us; speedup vs baseline: 1.9719x; 1.9719x over previous
//
#include <hip/hip_runtime.h>
#include <stdint.h>

#define T_MAX 512
#define BATCH 64
#define NCLS  128
#define BEAM  32
#define TBL   6144
#define NEGF  (-1e30f)
#define EMPTYK ((int)0x80000000)
#define HPRIME 1000003u

// jnp.logaddexp: max + log1p(exp(-|a-b|)) (all values finite here)
__device__ __forceinline__ float lae(float a, float b) {
  float mx = fmaxf(a, b);
  return mx + log1pf(expf(-fabsf(a - b)));
}
// monotonic float <-> uint mapping for ordering / atomicMax on floats
__device__ __forceinline__ unsigned encf(float x) {
  unsigned b = __float_as_uint(x);
  return (b & 0x80000000u) ? ~b : (b | 0x80000000u);
}
__device__ __forceinline__ float decf(unsigned u) {
  unsigned b = (u & 0x80000000u) ? (u ^ 0x80000000u) : ~u;
  return __uint_as_float(b);
}

__device__ __forceinline__ int tbl_insert(int* key, int h) {
  unsigned x = (unsigned)h * 2654435761u;
  x ^= x >> 16;
  int j = (int)(((unsigned long long)x * (unsigned long long)TBL) >> 32);
  for (;;) {
    int cur = key[j];
    if (cur == EMPTYK) cur = atomicCAS(&key[j], EMPTYK, h);
    if (cur == EMPTYK || cur == h) return j;
    ++j; if (j == TBL) j = 0;
  }
}

__global__ __launch_bounds__(512, 1)
void ctc_beam_kernel(const float* __restrict__ data,
                     const int* __restrict__ dlen,
                     int* __restrict__ out) {
  // rare-path hash table (96 KB) — only touched on anomaly steps
  __shared__ int       tkey[TBL];
  __shared__ unsigned  tmax[TBL];
  __shared__ unsigned  tsum[TBL];
  __shared__ unsigned  tmin[TBL];
  // shared state
  __shared__ unsigned short bp[T_MAX * BEAM];  // backptr: parent|cls<<5|ext<<12
  __shared__ float lp[NCLS];
  __shared__ int   bhash[2][BEAM];
  __shared__ float bpb[2][BEAM], bpnb[2][BEAM];
  __shared__ int   blen[2][BEAM], blast[2][BEAM];
  __shared__ float sptot[BEAM], s_pb[BEAM], s_pnb[BEAM], s_pnbm[BEAM];
  __shared__ int   stay_slot[BEAM];          // rare path only
  // fast-path merge structure
  __shared__ unsigned char mergeTo[BEAM * NCLS];  // 4 KB; 0xFF = none
  __shared__ int mergeCnt[BEAM], mergeFrom[BEAM]; // (i<<8)|c
  __shared__ int anom;
  // selection scratch
  __shared__ unsigned long long wkey[8 * BEAM];
  __shared__ unsigned widx[8 * BEAM];
  __shared__ unsigned sel[BEAM];
  __shared__ int seqbuf[T_MAX];
  __shared__ int flen_s;

  const int tid = threadIdx.x;
  const int b = blockIdx.x;
  int L = dlen[b];
  L = L < 0 ? 0 : (L > T_MAX ? T_MAX : L);

  if (tid < BEAM) {
    bhash[0][tid] = tid;                     // hashes0 = arange(W)
    bpb[0][tid]   = (tid == 0) ? 0.0f : NEGF;
    bpnb[0][tid]  = NEGF;
    blen[0][tid]  = 0;
    blast[0][tid] = -1;
  }
  __syncthreads();

  int cb = 0;
  for (int t = 0; t < L; ++t) {
    // ======== phase 0: clear merge structures, load log-probs ========
    {
      unsigned* mtw = (unsigned*)mergeTo;
      for (int m = tid; m < (BEAM * NCLS) / 4; m += 512) mtw[m] = 0xFFFFFFFFu;
    }
    if (tid < BEAM) mergeCnt[tid] = 0;
    if (tid == 0) anom = 0;
    if (tid < NCLS) lp[tid] = data[((size_t)t * BATCH + b) * NCLS + tid];
    __syncthreads();  // B1

    // ======== phase 1: stay values + exact merge detection ========
    if (tid < BEAM) {
      const float pbv = bpb[cb][tid], pnbv = bpnb[cb][tid];
      const float pt = lae(pbv, pnbv);
      sptot[tid] = pt;
      s_pb[tid]  = pt + lp[0];
      const int lsti = blast[cb][tid];
      s_pnb[tid] = pnbv + ((lsti >= 0) ? lp[lsti] : NEGF);
    }
    for (int k = tid; k < BEAM * BEAM; k += 512) {
      const int j = k >> 5, i2 = k & 31;
      const unsigned hj = (unsigned)bhash[cb][j];
      const unsigned hip = (unsigned)bhash[cb][i2] * HPRIME;
      const unsigned c = hj - hip - 1u;
      if (c < (unsigned)NCLS) {                       // extend(i2,c) merges stay j
        atomicAdd(&mergeCnt[j], 1);
        mergeFrom[j] = (i2 << 8) | (int)c;
        mergeTo[i2 * NCLS + (int)c] = (unsigned char)j;
      }
      if (j < i2) {                                    // extend-extend collision?
        const unsigned d = ((unsigned)bhash[cb][j] - (unsigned)bhash[cb][i2]) * HPRIME;
        if (d + 127u <= 254u) anom = 1;
      }
    }
    __syncthreads();  // B2
    if (tid < BEAM && mergeCnt[tid] > 1) anom = 1;     // >1 extend into one stay
    __syncthreads();  // B3

    const int i  = tid >> 4;             // beam owned by this thread (extends)
    const int c0 = (tid & 15) << 3;      // 8 consecutive classes

    if (!anom) {
      // ================= FAST PATH (no hash table) =================
      unsigned long long kk[9]; unsigned xx[9];
      {
        const float pbi = bpb[cb][i];
        const float pti = sptot[i];
        const int   lsti = blast[cb][i];
        const unsigned hb = (unsigned)bhash[cb][i] * HPRIME;
        const unsigned* mt = (const unsigned*)&mergeTo[i * NCLS + c0];
        const unsigned m0 = mt[0], m1 = mt[1];
        #pragma unroll
        for (int k = 0; k < 8; ++k) {
          const int c = c0 + k;
          const unsigned mb = ((k < 4 ? (m0 >> (8 * k)) : (m1 >> (8 * (k - 4)))) & 0xFFu);
          const float x = (c == 0) ? NEGF : (((c == lsti) ? pbi : pti) + lp[c]);
          const float tot = fmaxf(x, NEGF);   // == lae(NEGF, x) bitwise (see notes)
          const unsigned h = hb + (unsigned)(c + 1);
          unsigned long long key =
              ((unsigned long long)encf(tot) << 32) |
              (unsigned long long)(0xFFFFFFFFu - (h ^ 0x80000000u));
          if (mb != 0xFFu || c == 0) key = 0ull;   // merged into stay, or blank
          kk[k] = key;
          xx[k] = (unsigned)(BEAM + i * NCLS + c);
        }
      }
      if (tid < BEAM) {  // stay-rooted segment key + merged pnb_m
        const int j = tid;
        float pnbm;
        if (mergeCnt[j] == 1) {
          const int mf = mergeFrom[j];
          const int mi = mf >> 8, mc = mf & 255;
          const float e = (mc == 0) ? NEGF
              : (((mc == blast[cb][mi]) ? bpb[cb][mi] : sptot[mi]) + lp[mc]);
          const float a = s_pnb[j];
          const float m = fmaxf(a, e);
          const float s = expf(a - m) + expf(e - m);  // stay term first (ref order)
          pnbm = m + logf(s);
        } else {
          pnbm = s_pnb[j];
        }
        s_pnbm[j] = pnbm;
        const float tot = lae(s_pb[j], pnbm);
        const unsigned h = (unsigned)bhash[cb][j];
        kk[8] = ((unsigned long long)encf(tot) << 32) |
                (unsigned long long)(0xFFFFFFFFu - (h ^ 0x80000000u));
        xx[8] = (unsigned)j;
      } else { kk[8] = 0ull; xx[8] = 0u; }

      // local sort desc (static bubble network -> registers stay registers)
      #pragma unroll
      for (int p = 0; p < 8; ++p) {
        #pragma unroll
        for (int q = 0; q < 8; ++q) {
          if (q < 8 - p) {
            if (kk[q] < kk[q + 1]) {
              unsigned long long tk = kk[q]; kk[q] = kk[q + 1]; kk[q + 1] = tk;
              unsigned tx = xx[q]; xx[q] = xx[q + 1]; xx[q + 1] = tx;
            }
          }
        }
      }

      // per-wave ordered top-32 via pop (heads are lane-local maxima)
      {
        const int wv = tid >> 6, ln = tid & 63;
        for (int it = 0; it < BEAM; ++it) {
          unsigned long long wm = kk[0];
          #pragma unroll
          for (int off = 32; off > 0; off >>= 1) {
            const unsigned long long o = __shfl_xor(wm, off, 64);
            if (o > wm) wm = o;
          }
          const unsigned long long ball = __ballot(kk[0] == wm && wm != 0ull);
          const int winner = ball ? (__ffsll((long long)ball) - 1) : -1;
          if (ln == winner) {
            wkey[wv * BEAM + it] = kk[0];
            widx[wv * BEAM + it] = xx[0];
            #pragma unroll
            for (int q = 0; q < 8; ++q) { kk[q] = kk[q + 1]; xx[q] = xx[q + 1]; }
            kk[8] = 0ull;
          } else if (winner < 0 && ln == 0) {
            wkey[wv * BEAM + it] = 0ull;
            widx[wv * BEAM + it] = 0xFFFFFFFFu;
          }
        }
      }
      __syncthreads();  // B4

      // wave 0: pop-merge 8 sorted lists (4 consecutive entries per lane)
      if (tid < 64) {
        unsigned long long mk[4]; unsigned mx[4];
        #pragma unroll
        for (int m = 0; m < 4; ++m) { mk[m] = wkey[tid * 4 + m]; mx[m] = widx[tid * 4 + m]; }
        for (int it = 0; it < BEAM; ++it) {
          unsigned long long wm = mk[0];
          #pragma unroll
          for (int off = 32; off > 0; off >>= 1) {
            const unsigned long long o = __shfl_xor(wm, off, 64);
            if (o > wm) wm = o;
          }
          const unsigned long long ball = __ballot(mk[0] == wm && wm != 0ull);
          const int winner = ball ? (__ffsll((long long)ball) - 1) : -1;
          if (tid == winner) {
            sel[it] = mx[0];
            #pragma unroll
            for (int q = 0; q < 3; ++q) { mk[q] = mk[q + 1]; mx[q] = mx[q + 1]; }
            mk[3] = 0ull;
          } else if (winner < 0 && tid == 0) {
            sel[it] = 0xFFFFFFFFu;
          }
        }
      }
      __syncthreads();  // B5

      // update beam state
      if (tid < BEAM) {
        const int j = tid;
        const unsigned s = sel[j];
        int nh, p, cls, ex; float npb, npnb;
        if (s < BEAM) {                     // stay-rooted segment: head = stay
          p = (int)s; cls = 0; ex = 0;
          nh = bhash[cb][p];
          npb = s_pb[p];
          npnb = s_pnbm[p];
        } else if (s != 0xFFFFFFFFu) {      // standalone extend
          const unsigned q = s - BEAM;
          p = (int)(q >> 7); cls = (int)(q & 127); ex = 1;
          nh = (int)((unsigned)bhash[cb][p] * HPRIME + (unsigned)(cls + 1));
          npb = NEGF;
          npnb = (cls == 0) ? NEGF
               : (((cls == blast[cb][p]) ? bpb[cb][p] : sptot[p]) + lp[cls]);
        } else {                            // unreachable safety
          nh = 0x7F000000 + j; npb = NEGF; npnb = NEGF; p = j; cls = 0; ex = 0;
        }
        const int plen = blen[cb][p], plast = blast[cb][p];
        const int nb = cb ^ 1;
        bhash[nb][j] = nh; bpb[nb][j] = npb; bpnb[nb][j] = npnb;
        blen[nb][j]  = plen + ex;
        blast[nb][j] = ex ? cls : plast;
        bp[t * BEAM + j] = (unsigned short)(p | (cls << 5) | (ex << 12));
      }
      __syncthreads();  // B6
    } else {
      // ================= RARE PATH: full hash table (proven R1 code) =========
      for (int m = tid; m < TBL; m += 512) {
        tkey[m] = EMPTYK; tmax[m] = 0u; tsum[m] = 0u; tmin[m] = 0xFFFFFFFFu;
      }
      __syncthreads();

      int eslot[8]; float ex_[8];
      {
        const float pbi = bpb[cb][i];
        const float pti = sptot[i];
        const int   lsti = blast[cb][i];
        const unsigned hb = (unsigned)bhash[cb][i] * HPRIME;
        #pragma unroll
        for (int k = 0; k < 8; ++k) {
          const int c = c0 + k;
          int h = (int)(hb + (unsigned)(c + 1));
          if (h == EMPTYK) h = (int)0x80000001u;
          const float x = (c == 0) ? NEGF : (((c == lsti) ? pbi : pti) + lp[c]);
          const int s = tbl_insert(tkey, h);
          atomicMax(&tmax[s], encf(x));
          atomicMin(&tmin[s], (unsigned)(BEAM + i * NCLS + c));
          eslot[k] = s; ex_[k] = x;
        }
      }
      if (tid < BEAM) {
        const int s = tbl_insert(tkey, bhash[cb][tid]);
        atomicMax(&tmax[s], encf(s_pnb[tid]));
        atomicMin(&tmin[s], (unsigned)tid);
        stay_slot[tid] = s;
      }
      __syncthreads();

      #pragma unroll
      for (int k = 0; k < 8; ++k) {
        const int s = eslot[k];
        atomicAdd((float*)&tsum[s], expf(ex_[k] - decf(tmax[s])));
      }
      if (tid < BEAM) {
        const int s = stay_slot[tid];
        atomicAdd((float*)&tsum[s], expf(s_pnb[tid] - decf(tmax[s])));
      }
      __syncthreads();

      for (int m = tid; m < TBL; m += 512) {
        if (tkey[m] != EMPTYK) {
          const float mm = decf(tmax[m]);
          const float ss = __uint_as_float(tsum[m]);
          const float pnbm = mm + logf(ss);
          tmax[m] = __float_as_uint(pnbm);
          tsum[m] = encf(lae(NEGF, pnbm));
        }
      }
      __syncthreads();
      if (tid < BEAM) {
        const int s = stay_slot[tid];
        tsum[s] = encf(lae(s_pb[tid], __uint_as_float(tmax[s])));
      }
      __syncthreads();

      {
        const int wv = tid >> 6, ln = tid & 63;
        const int base = wv * (TBL / 8) + ln * (TBL / 512);
        unsigned long long kk2[TBL / 512];
        #pragma unroll
        for (int m = 0; m < TBL / 512; ++m) {
          const int idx = base + m;
          if (tkey[idx] != EMPTYK) {
            const unsigned hh = (unsigned)tkey[idx] ^ 0x80000000u;
            kk2[m] = ((unsigned long long)tsum[idx] << 32) |
                     (unsigned long long)(0xFFFFFFFFu - hh);
          } else kk2[m] = 0ull;
        }
        unsigned cons = 0;
        for (int it = 0; it < BEAM; ++it) {
          unsigned long long best = 0ull; int bi = -1;
          #pragma unroll
          for (int m = 0; m < TBL / 512; ++m)
            if (!((cons >> m) & 1u) && kk2[m] > best) { best = kk2[m]; bi = m; }
          unsigned long long wm = best;
          #pragma unroll
          for (int off = 32; off > 0; off >>= 1) {
            const unsigned long long o = __shfl_xor(wm, off, 64);
            if (o > wm) wm = o;
          }
          const unsigned long long ball = __ballot(best == wm && wm != 0ull);
          const int winner = ball ? (__ffsll((long long)ball) - 1) : -1;
          if (ln == winner) {
            cons |= 1u << bi;
            wkey[wv * BEAM + it] = wm;
            widx[wv * BEAM + it] = (unsigned)(base + bi);
          } else if (winner < 0 && ln == 0) {
            wkey[wv * BEAM + it] = 0ull;
            widx[wv * BEAM + it] = 0xFFFFFFFFu;
          }
        }
      }
      __syncthreads();
      if (tid < 64) {
        unsigned long long kk2[4]; unsigned ii[4];
        #pragma unroll
        for (int m = 0; m < 4; ++m) { kk2[m] = wkey[tid * 4 + m]; ii[m] = widx[tid * 4 + m]; }
        unsigned cons = 0;
        for (int it = 0; it < BEAM; ++it) {
          unsigned long long best = 0ull; int bi = -1;
          #pragma unroll
          for (int m = 0; m < 4; ++m)
            if (!((cons >> m) & 1u) && kk2[m] > best) { best = kk2[m]; bi = m; }
          unsigned long long wm = best;
          #pragma unroll
          for (int off = 32; off > 0; off >>= 1) {
            const unsigned long long o = __shfl_xor(wm, off, 64);
            if (o > wm) wm = o;
          }
          const unsigned long long ball = __ballot(best == wm && wm != 0ull);
          const int winner = ball ? (__ffsll((long long)ball) - 1) : -1;
          if (tid == winner) { cons |= 1u << bi; sel[it] = ii[bi]; }
          else if (winner < 0 && tid == 0) sel[it] = 0xFFFFFFFFu;
        }
      }
      __syncthreads();

      if (tid < BEAM) {
        const int j = tid;
        const unsigned s = sel[j];
        int nh, p, cls, ex; float npb, npnb;
        if (s != 0xFFFFFFFFu) {
          nh = tkey[s];
          npnb = __uint_as_float(tmax[s]);
          npb = NEGF;
          #pragma unroll
          for (int q = 0; q < BEAM; ++q)
            if (stay_slot[q] == (int)s) npb = s_pb[q];
          const unsigned mi = tmin[s];
          ex  = (mi >= BEAM) ? 1 : 0;
          p   = ex ? (int)((mi - BEAM) >> 7) : (int)mi;
          cls = ex ? (int)((mi - BEAM) & 127) : 0;
          p &= 31;
        } else {
          nh = 0x7F000000 + j; npb = NEGF; npnb = NEGF; p = j; cls = 0; ex = 0;
        }
        const int plen = blen[cb][p], plast = blast[cb][p];
        const int nb = cb ^ 1;
        bhash[nb][j] = nh; bpb[nb][j] = npb; bpnb[nb][j] = npnb;
        blen[nb][j]  = plen + ex;
        blast[nb][j] = ex ? cls : plast;
        bp[t * BEAM + j] = (unsigned short)(p | (cls << 5) | (ex << 12));
      }
      __syncthreads();
    }
    cb ^= 1;
  }

  // ---- final top-1 + path reconstruction via backpointers
  if (tid == 0) {
    float bt = -3.4e38f; int bj = 0;
    for (int j = 0; j < BEAM; ++j) {
      const float tt = lae(bpb[cb][j], bpnb[cb][j]);
      if (tt > bt) { bt = tt; bj = j; }   // strict > : lowest index wins ties
    }
    int cur = bj;
    int pos = blen[cb][bj];
    flen_s = pos;
    for (int tt = L - 1; tt >= 0; --tt) {
      const unsigned short e = bp[tt * BEAM + cur];
      const int p = e & 31, cl = (e >> 5) & 127, ex = (e >> 12) & 1;
      if (ex) { --pos; if (pos >= 0) seqbuf[pos] = cl; }
      cur = p;
    }
  }
  __syncthreads();
  const int fl = flen_s;
  for (int k = tid; k < T_MAX; k += 512) {
    out[(size_t)b * T_MAX + k] = (k < fl) ? seqbuf[k] : 0;
  }
}

extern "C" void kernel_launch(void* const* d_in, const int* in_sizes, int n_in,
                              void* d_out, int out_size, void* d_ws, size_t ws_size,
                              hipStream_t stream) {
  const float* data = (const float*)d_in[0];   // [512, 64, 128] f32 log-probs
  const int*   dlen = (const int*)d_in[1];     // [64] int32
  int* out = (int*)d_out;                      // [64, 512] int32
  (void)in_sizes; (void)n_in; (void)out_size; (void)d_ws; (void)ws_size;
  hipLaunchKernelGGL(ctc_beam_kernel, dim3(BATCH), dim3(512), 0, stream,
                     data, dlen, out);
}

// Round 3
// 2977.834 us; speedup vs baseline: 10.1854x; 5.1653x over previous
//
#include <hip/hip_runtime.h>
#include <stdint.h>

#define T_MAX 512
#define BATCH 64
#define NCLS  128
#define BEAM  32
#define TBL   6144
#define NEGF  (-1e30f)
#define EMPTYK ((int)0x80000000)
#define HPRIME 1000003u
#define SCAP  256

// jnp.logaddexp: max + log1p(exp(-|a-b|)) (all values finite here)
__device__ __forceinline__ float lae(float a, float b) {
  float mx = fmaxf(a, b);
  return mx + log1pf(expf(-fabsf(a - b)));
}
// monotonic float <-> uint mapping for ordering / atomicMax on floats
__device__ __forceinline__ unsigned encf(float x) {
  unsigned b = __float_as_uint(x);
  return (b & 0x80000000u) ? ~b : (b | 0x80000000u);
}
__device__ __forceinline__ float decf(unsigned u) {
  unsigned b = (u & 0x80000000u) ? (u ^ 0x80000000u) : ~u;
  return __uint_as_float(b);
}

__device__ __forceinline__ int tbl_insert(int* key, int h) {
  unsigned x = (unsigned)h * 2654435761u;
  x ^= x >> 16;
  int j = (int)(((unsigned long long)x * (unsigned long long)TBL) >> 32);
  for (;;) {
    int cur = key[j];
    if (cur == EMPTYK) cur = atomicCAS(&key[j], EMPTYK, h);
    if (cur == EMPTYK || cur == h) return j;
    ++j; if (j == TBL) j = 0;
  }
}

__device__ __forceinline__ unsigned long long shflx64(unsigned long long v, int m) {
  unsigned lo = (unsigned)__shfl_xor((int)(unsigned)v, m, 64);
  unsigned hi = (unsigned)__shfl_xor((int)(unsigned)(v >> 32), m, 64);
  return ((unsigned long long)hi << 32) | lo;
}

// Descending bitonic sort of N elements across one wave (64 lanes), blocked
// layout: global index g = lane*R + r. WX: carry a 32-bit payload.
template<int N, bool WX>
__device__ __forceinline__ void bitsortN(int ln, unsigned long long* k, unsigned* x) {
  constexpr int R = N / 64;
  #pragma unroll
  for (int size = 2; size <= N; size <<= 1) {
    #pragma unroll
    for (int stride = size >> 1; stride > 0; stride >>= 1) {
      if (stride >= R) {               // cross-lane exchange, same r
        const int ls = stride / R;
        #pragma unroll
        for (int r = 0; r < R; ++r) {
          const bool desc = (((ln * R + r) & size) == 0);
          const bool low  = ((ln & ls) == 0);
          const bool keepMax = (desc == low);
          const unsigned long long pk = shflx64(k[r], ls);
          unsigned px = 0;
          if (WX) px = (unsigned)__shfl_xor((int)x[r], ls, 64);
          const bool take = keepMax ? (pk > k[r]) : (pk < k[r]);
          if (take) { k[r] = pk; if (WX) x[r] = px; }
        }
      } else {                          // intra-lane compare-exchange
        #pragma unroll
        for (int r = 0; r < R; ++r) {
          const int q = r ^ stride;
          if (q > r) {
            const bool desc = (((ln * R + r) & size) == 0);
            const bool sw = desc ? (k[q] > k[r]) : (k[r] > k[q]);
            if (sw) {
              unsigned long long tk = k[r]; k[r] = k[q]; k[q] = tk;
              if (WX) { unsigned tx = x[r]; x[r] = x[q]; x[q] = tx; }
            }
          }
        }
      }
    }
  }
}

__global__ __launch_bounds__(512, 1)
void ctc_beam_kernel(const float* __restrict__ data,
                     const int* __restrict__ dlen,
                     int* __restrict__ out) {
  // rare-path hash table — touched only at t==0 / anomalies / overflow
  __shared__ int       tkey[TBL];
  __shared__ unsigned  tmax[TBL];
  __shared__ unsigned  tsum[TBL];
  __shared__ unsigned  tmin[TBL];
  __shared__ unsigned short bp[T_MAX * BEAM];  // backptr: parent|cls<<5|ext<<12
  __shared__ float lpbuf[2][NCLS];
  __shared__ int   bhash[2][BEAM];
  __shared__ float bpb[2][BEAM], bpnb[2][BEAM];
  __shared__ int   blen[2][BEAM], blast[2][BEAM];
  __shared__ float sptot[BEAM], s_pb[BEAM], s_pnb[BEAM], s_pnbm[BEAM];
  __shared__ int   stay_slot[BEAM];
  __shared__ unsigned char mergeTo[BEAM * NCLS];  // 0xFF = not merged
  __shared__ int mergeCnt[BEAM], mergeFrom[BEAM];
  __shared__ unsigned parentBest[BEAM];   // enc32 of best standalone extend
  __shared__ unsigned s_key32[BEAM];      // enc32 of stay tot
  __shared__ int anom, ovf, scnt;
  __shared__ unsigned thr_s;
  __shared__ unsigned long long skey[SCAP];
  __shared__ unsigned sidx[SCAP];
  // rare-path selection scratch
  __shared__ unsigned long long wkey[8 * BEAM];
  __shared__ unsigned widx[8 * BEAM];
  __shared__ unsigned sel[BEAM];
  __shared__ int seqbuf[T_MAX];
  __shared__ int flen_s;

  const int tid = threadIdx.x;
  const int b = blockIdx.x;
  int L = dlen[b];
  L = L < 0 ? 0 : (L > T_MAX ? T_MAX : L);

  if (tid < BEAM) {
    bhash[0][tid] = tid;
    bpb[0][tid]   = (tid == 0) ? 0.0f : NEGF;
    bpnb[0][tid]  = NEGF;
    blen[0][tid]  = 0;
    blast[0][tid] = -1;
  }
  if (tid < NCLS && L > 0) lpbuf[0][tid] = data[(size_t)b * NCLS + tid];
  __syncthreads();

  int cb = 0;
  for (int t = 0; t < L; ++t) {
    // prefetch next timestep's log-probs (latency hides under the step)
    const bool haspre = (tid < NCLS) && (t + 1 < L);
    float pre = 0.0f;
    if (haspre) pre = data[((size_t)(t + 1) * BATCH + b) * NCLS + tid];

    float* lpc = lpbuf[t & 1];
    // ---- clear + stays ----
    {
      unsigned* mtw = (unsigned*)mergeTo;
      for (int m = tid; m < (BEAM * NCLS) / 4; m += 512) mtw[m] = 0xFFFFFFFFu;
    }
    if (tid < BEAM) { mergeCnt[tid] = 0; parentBest[tid] = 0u; }
    if (tid == 0) { anom = (t == 0) ? 1 : 0; ovf = 0; scnt = 0; }
    if (tid < BEAM) {
      const float pbv = bpb[cb][tid], pnbv = bpnb[cb][tid];
      const float pt = lae(pbv, pnbv);
      sptot[tid] = pt;
      s_pb[tid]  = pt + lpc[0];
      const int lsti = blast[cb][tid];
      s_pnb[tid] = pnbv + ((lsti >= 0) ? lpc[lsti] : NEGF);
    }
    __syncthreads();  // B1

    // ---- exact merge detection (extend(i2,c) == stay j iff h_j = h_i2*P+c+1)
    for (int k = tid; k < BEAM * BEAM; k += 512) {
      const int j = k >> 5, i2 = k & 31;
      const unsigned hj = (unsigned)bhash[cb][j];
      const unsigned hip = (unsigned)bhash[cb][i2] * HPRIME;
      const unsigned c = hj - hip - 1u;
      if (c < (unsigned)NCLS) {
        atomicAdd(&mergeCnt[j], 1);
        mergeFrom[j] = (i2 << 8) | (int)c;
        mergeTo[i2 * NCLS + (int)c] = (unsigned char)j;
      }
      if (j < i2) {   // extend-extend collision anywhere in class range?
        const unsigned d = ((unsigned)bhash[cb][j] - (unsigned)bhash[cb][i2]) * HPRIME;
        if (d + 127u <= 254u) anom = 1;
      }
    }
    __syncthreads();  // B2

    // ---- per-thread extend keys + per-parent best; stay keys ----
    const int i  = tid >> 4;
    const int c0 = (tid & 15) << 3;
    unsigned long long k8[8];
    {
      const float pbi = bpb[cb][i];
      const float pti = sptot[i];
      const int   lsti = blast[cb][i];
      const unsigned hb = (unsigned)bhash[cb][i] * HPRIME;
      const float4 l0 = ((const float4*)(lpc + c0))[0];
      const float4 l1 = ((const float4*)(lpc + c0))[1];
      const float lv[8] = {l0.x, l0.y, l0.z, l0.w, l1.x, l1.y, l1.z, l1.w};
      const unsigned m0 = ((const unsigned*)&mergeTo[i * NCLS + c0])[0];
      const unsigned m1 = ((const unsigned*)&mergeTo[i * NCLS + c0])[1];
      unsigned pbest = 0u;
      #pragma unroll
      for (int k = 0; k < 8; ++k) {
        const int c = c0 + k;
        const unsigned mb = ((k < 4 ? (m0 >> (8 * k)) : (m1 >> (8 * (k - 4)))) & 0xFFu);
        const float x = (c == 0) ? NEGF : (((c == lsti) ? pbi : pti) + lv[k]);
        const float tot = fmaxf(x, NEGF);   // == lae(NEGF,x) bitwise
        const unsigned h = hb + (unsigned)(c + 1);
        unsigned long long key =
            ((unsigned long long)encf(tot) << 32) |
            (unsigned long long)(0xFFFFFFFFu - (h ^ 0x80000000u));
        if (mb != 0xFFu || c == 0) key = 0ull;   // merged into a stay, or blank
        k8[k] = key;
        const unsigned e32 = (unsigned)(key >> 32);
        pbest = pbest > e32 ? pbest : e32;
      }
      atomicMax(&parentBest[i], pbest);
    }
    if (tid < BEAM) {
      const int j = tid;
      if (mergeCnt[j] > 1) anom = 1;
      float pnbm;
      if (mergeCnt[j] == 1) {
        const int mf = mergeFrom[j];
        const int mi = mf >> 8, mc = mf & 255;
        const float e = (mc == 0) ? NEGF
            : (((mc == blast[cb][mi]) ? bpb[cb][mi] : sptot[mi]) + lpc[mc]);
        const float a = s_pnb[j];
        const float m = fmaxf(a, e);
        const float s = expf(a - m) + expf(e - m);  // stay term first (ref order)
        pnbm = m + logf(s);
      } else {
        pnbm = s_pnb[j];
      }
      s_pnbm[j] = pnbm;
      s_key32[j] = encf(lae(s_pb[j], pnbm));
    }
    __syncthreads();  // B3

    bool dorare = (anom != 0);
    if (!dorare) {
      // ---- theta = exact 32nd largest of {stay tots} U {parent best extends}
      if (tid < 64) {
        unsigned long long kv = (tid < BEAM) ? (unsigned long long)s_key32[tid]
                                             : (unsigned long long)parentBest[tid - BEAM];
        unsigned dx = 0;
        bitsortN<64, false>(tid, &kv, &dx);
        if (tid == 31) thr_s = (unsigned)kv;
      }
      __syncthreads();  // B4
      const unsigned thr = thr_s;
      // ---- filter + compact survivors (true top-32 guaranteed kept)
      #pragma unroll
      for (int k = 0; k < 8; ++k) {
        if ((unsigned)(k8[k] >> 32) >= thr) {
          const int a = atomicAdd(&scnt, 1);
          if (a < SCAP) { skey[a] = k8[k]; sidx[a] = (unsigned)(BEAM + i * NCLS + (c0 + k)); }
          else ovf = 1;
        }
      }
      if (tid < BEAM && s_key32[tid] >= thr) {
        const int a = atomicAdd(&scnt, 1);
        if (a < SCAP) {
          skey[a] = ((unsigned long long)s_key32[tid] << 32) |
                    (unsigned long long)(0xFFFFFFFFu - ((unsigned)bhash[cb][tid] ^ 0x80000000u));
          sidx[a] = (unsigned)tid;
        } else ovf = 1;
      }
      __syncthreads();  // B5
      if (ovf) dorare = true;
    }

    if (!dorare) {
      // ---- sort survivors desc by (tot, hash-order); take ordered top-32
      const int sc = scnt < SCAP ? scnt : SCAP;
      if (tid < 64) {
        const int ln = tid;
        if (sc <= 64) {
          unsigned long long k1[1]; unsigned x1[1];
          k1[0] = (ln < sc) ? skey[ln] : 0ull;
          x1[0] = (ln < sc) ? sidx[ln] : 0xFFFFFFFFu;
          bitsortN<64, true>(ln, k1, x1);
          if (ln < BEAM) sel[ln] = x1[0];
        } else if (sc <= 128) {
          unsigned long long k2[2]; unsigned x2[2];
          #pragma unroll
          for (int r = 0; r < 2; ++r) {
            const int g = ln * 2 + r;
            k2[r] = (g < sc) ? skey[g] : 0ull;
            x2[r] = (g < sc) ? sidx[g] : 0xFFFFFFFFu;
          }
          bitsortN<128, true>(ln, k2, x2);
          #pragma unroll
          for (int r = 0; r < 2; ++r) { const int g = ln * 2 + r; if (g < BEAM) sel[g] = x2[r]; }
        } else {
          unsigned long long k4[4]; unsigned x4[4];
          #pragma unroll
          for (int r = 0; r < 4; ++r) {
            const int g = ln * 4 + r;
            k4[r] = (g < sc) ? skey[g] : 0ull;
            x4[r] = (g < sc) ? sidx[g] : 0xFFFFFFFFu;
          }
          bitsortN<256, true>(ln, k4, x4);
          #pragma unroll
          for (int r = 0; r < 4; ++r) { const int g = ln * 4 + r; if (g < BEAM) sel[g] = x4[r]; }
        }
      }
      __syncthreads();  // B6

      // ---- update beam state
      if (tid < BEAM) {
        const int j = tid;
        const unsigned s = sel[j];
        int nh, p, cls, ex; float npb, npnb;
        if (s < BEAM) {                     // stay-rooted segment
          p = (int)s; cls = 0; ex = 0;
          nh = bhash[cb][p];
          npb = s_pb[p];
          npnb = s_pnbm[p];
        } else if (s != 0xFFFFFFFFu) {      // standalone extend
          const unsigned q = s - BEAM;
          p = (int)(q >> 7); cls = (int)(q & 127); ex = 1;
          nh = (int)((unsigned)bhash[cb][p] * HPRIME + (unsigned)(cls + 1));
          npb = NEGF;
          npnb = (cls == 0) ? NEGF
               : (((cls == blast[cb][p]) ? bpb[cb][p] : sptot[p]) + lpc[cls]);
        } else {                            // unreachable safety
          nh = 0x7F000000 + j; npb = NEGF; npnb = NEGF; p = j; cls = 0; ex = 0;
        }
        const int plen = blen[cb][p], plast = blast[cb][p];
        const int nb = cb ^ 1;
        bhash[nb][j] = nh; bpb[nb][j] = npb; bpnb[nb][j] = npnb;
        blen[nb][j]  = plen + ex;
        blast[nb][j] = ex ? cls : plast;
        bp[t * BEAM + j] = (unsigned short)(p | (cls << 5) | (ex << 12));
      }
      if (haspre) lpbuf[(t + 1) & 1][tid] = pre;
      __syncthreads();  // B7
    }

    if (dorare) {
      // ================= RARE PATH: full hash table (proven R1 code) =========
      for (int m = tid; m < TBL; m += 512) {
        tkey[m] = EMPTYK; tmax[m] = 0u; tsum[m] = 0u; tmin[m] = 0xFFFFFFFFu;
      }
      __syncthreads();

      int eslot[8]; float ex_[8];
      {
        const float pbi = bpb[cb][i];
        const float pti = sptot[i];
        const int   lsti = blast[cb][i];
        const unsigned hb = (unsigned)bhash[cb][i] * HPRIME;
        #pragma unroll
        for (int k = 0; k < 8; ++k) {
          const int c = c0 + k;
          int h = (int)(hb + (unsigned)(c + 1));
          if (h == EMPTYK) h = (int)0x80000001u;
          const float x = (c == 0) ? NEGF : (((c == lsti) ? pbi : pti) + lpc[c]);
          const int s = tbl_insert(tkey, h);
          atomicMax(&tmax[s], encf(x));
          atomicMin(&tmin[s], (unsigned)(BEAM + i * NCLS + c));
          eslot[k] = s; ex_[k] = x;
        }
      }
      if (tid < BEAM) {
        const int s = tbl_insert(tkey, bhash[cb][tid]);
        atomicMax(&tmax[s], encf(s_pnb[tid]));
        atomicMin(&tmin[s], (unsigned)tid);
        stay_slot[tid] = s;
      }
      __syncthreads();

      #pragma unroll
      for (int k = 0; k < 8; ++k) {
        const int s = eslot[k];
        atomicAdd((float*)&tsum[s], expf(ex_[k] - decf(tmax[s])));
      }
      if (tid < BEAM) {
        const int s = stay_slot[tid];
        atomicAdd((float*)&tsum[s], expf(s_pnb[tid] - decf(tmax[s])));
      }
      __syncthreads();

      for (int m = tid; m < TBL; m += 512) {
        if (tkey[m] != EMPTYK) {
          const float mm = decf(tmax[m]);
          const float ss = __uint_as_float(tsum[m]);
          const float pnbm = mm + logf(ss);
          tmax[m] = __float_as_uint(pnbm);
          tsum[m] = encf(lae(NEGF, pnbm));
        }
      }
      __syncthreads();
      if (tid < BEAM) {
        const int s = stay_slot[tid];
        tsum[s] = encf(lae(s_pb[tid], __uint_as_float(tmax[s])));
      }
      __syncthreads();

      {
        const int wv = tid >> 6, ln = tid & 63;
        const int base = wv * (TBL / 8) + ln * (TBL / 512);
        unsigned long long kk2[TBL / 512];
        #pragma unroll
        for (int m = 0; m < TBL / 512; ++m) {
          const int idx = base + m;
          if (tkey[idx] != EMPTYK) {
            const unsigned hh = (unsigned)tkey[idx] ^ 0x80000000u;
            kk2[m] = ((unsigned long long)tsum[idx] << 32) |
                     (unsigned long long)(0xFFFFFFFFu - hh);
          } else kk2[m] = 0ull;
        }
        unsigned cons = 0;
        for (int it = 0; it < BEAM; ++it) {
          unsigned long long best = 0ull; int bi = -1;
          #pragma unroll
          for (int m = 0; m < TBL / 512; ++m)
            if (!((cons >> m) & 1u) && kk2[m] > best) { best = kk2[m]; bi = m; }
          unsigned long long wm = best;
          #pragma unroll
          for (int off = 32; off > 0; off >>= 1) {
            const unsigned long long o = __shfl_xor(wm, off, 64);
            if (o > wm) wm = o;
          }
          const unsigned long long ball = __ballot(best == wm && wm != 0ull);
          const int winner = ball ? (__ffsll((long long)ball) - 1) : -1;
          if (ln == winner) {
            cons |= 1u << bi;
            wkey[wv * BEAM + it] = wm;
            widx[wv * BEAM + it] = (unsigned)(base + bi);
          } else if (winner < 0 && ln == 0) {
            wkey[wv * BEAM + it] = 0ull;
            widx[wv * BEAM + it] = 0xFFFFFFFFu;
          }
        }
      }
      __syncthreads();
      if (tid < 64) {
        unsigned long long kk2[4]; unsigned ii[4];
        #pragma unroll
        for (int m = 0; m < 4; ++m) { kk2[m] = wkey[tid * 4 + m]; ii[m] = widx[tid * 4 + m]; }
        unsigned cons = 0;
        for (int it = 0; it < BEAM; ++it) {
          unsigned long long best = 0ull; int bi = -1;
          #pragma unroll
          for (int m = 0; m < 4; ++m)
            if (!((cons >> m) & 1u) && kk2[m] > best) { best = kk2[m]; bi = m; }
          unsigned long long wm = best;
          #pragma unroll
          for (int off = 32; off > 0; off >>= 1) {
            const unsigned long long o = __shfl_xor(wm, off, 64);
            if (o > wm) wm = o;
          }
          const unsigned long long ball = __ballot(best == wm && wm != 0ull);
          const int winner = ball ? (__ffsll((long long)ball) - 1) : -1;
          if (tid == winner) { cons |= 1u << bi; sel[it] = ii[bi]; }
          else if (winner < 0 && tid == 0) sel[it] = 0xFFFFFFFFu;
        }
      }
      __syncthreads();

      if (tid < BEAM) {
        const int j = tid;
        const unsigned s = sel[j];
        int nh, p, cls, ex; float npb, npnb;
        if (s != 0xFFFFFFFFu) {
          nh = tkey[s];
          npnb = __uint_as_float(tmax[s]);
          npb = NEGF;
          #pragma unroll
          for (int q = 0; q < BEAM; ++q)
            if (stay_slot[q] == (int)s) npb = s_pb[q];
          const unsigned mi = tmin[s];
          ex  = (mi >= BEAM) ? 1 : 0;
          p   = ex ? (int)((mi - BEAM) >> 7) : (int)mi;
          cls = ex ? (int)((mi - BEAM) & 127) : 0;
          p &= 31;
        } else {
          nh = 0x7F000000 + j; npb = NEGF; npnb = NEGF; p = j; cls = 0; ex = 0;
        }
        const int plen = blen[cb][p], plast = blast[cb][p];
        const int nb = cb ^ 1;
        bhash[nb][j] = nh; bpb[nb][j] = npb; bpnb[nb][j] = npnb;
        blen[nb][j]  = plen + ex;
        blast[nb][j] = ex ? cls : plast;
        bp[t * BEAM + j] = (unsigned short)(p | (cls << 5) | (ex << 12));
      }
      if (haspre) lpbuf[(t + 1) & 1][tid] = pre;
      __syncthreads();
    }
    cb ^= 1;
  }

  // ---- final top-1 + path reconstruction via backpointers
  if (tid == 0) {
    float bt = -3.4e38f; int bj = 0;
    for (int j = 0; j < BEAM; ++j) {
      const float tt = lae(bpb[cb][j], bpnb[cb][j]);
      if (tt > bt) { bt = tt; bj = j; }   // strict > : lowest index wins ties
    }
    int cur = bj;
    int pos = blen[cb][bj];
    flen_s = pos;
    for (int tt = L - 1; tt >= 0; --tt) {
      const unsigned short e = bp[tt * BEAM + cur];
      const int p = e & 31, cl = (e >> 5) & 127, ex = (e >> 12) & 1;
      if (ex) { --pos; if (pos >= 0) seqbuf[pos] = cl; }
      cur = p;
    }
  }
  __syncthreads();
  const int fl = flen_s;
  for (int k = tid; k < T_MAX; k += 512) {
    out[(size_t)b * T_MAX + k] = (k < fl) ? seqbuf[k] : 0;
  }
}

extern "C" void kernel_launch(void* const* d_in, const int* in_sizes, int n_in,
                              void* d_out, int out_size, void* d_ws, size_t ws_size,
                              hipStream_t stream) {
  const float* data = (const float*)d_in[0];   // [512, 64, 128] f32 log-probs
  const int*   dlen = (const int*)d_in[1];     // [64] int32
  int* out = (int*)d_out;                      // [64, 512] int32
  (void)in_sizes; (void)n_in; (void)out_size; (void)d_ws; (void)ws_size;
  hipLaunchKernelGGL(ctc_beam_kernel, dim3(BATCH), dim3(512), 0, stream,
                     data, dlen, out);
}